// Round 1
// 267.446 us; speedup vs baseline: 1.2582x; 1.2582x over previous
//
#include <hip/hip_runtime.h>

// ---------- bf16 helpers ----------
__device__ __forceinline__ unsigned short f2bf(float f) {
    unsigned int x = __float_as_uint(f);
    x += 0x7fffu + ((x >> 16) & 1u);
    return (unsigned short)(x >> 16);
}
__device__ __forceinline__ float2 bf2x(unsigned int u) {
    float2 r;
    r.x = __uint_as_float(u << 16);
    r.y = __uint_as_float(u & 0xffff0000u);
    return r;
}

typedef __attribute__((ext_vector_type(8))) short frag8;   // 8 bf16
typedef __attribute__((ext_vector_type(4))) float fragf4;  // 4 fp32 acc

// ---------- convert 6 weight matrices [128x128] fp32 -> bf16, permuted ----------
// order: [Qa, Ka, Wt, Qb, Kb, Wx]
// Permuted fragment layout: element (row, col) of matrix m is stored at
//   m*16384 + ((ct*4 + ks)*64 + quad*16 + li)*8 + j
// where ct=row>>4, li=row&15, ks=col>>5, quad=(col>>3)&3, j=col&7.
// Then a wave's MFMA A-fragment load for (ct,ks) is base + lane*16 bytes:
// one fully coalesced 1 KB read.
__global__ __launch_bounds__(256) void convert_w(
    const float* __restrict__ s0, const float* __restrict__ s1,
    const float* __restrict__ s2, const float* __restrict__ s3,
    const float* __restrict__ s4, const float* __restrict__ s5,
    unsigned short* __restrict__ dst)
{
    int id = blockIdx.x * 256 + threadIdx.x;
    int m = id >> 12;
    int e = (id & 4095) * 4;
    const float* s = (m == 0) ? s0 : (m == 1) ? s1 : (m == 2) ? s2
                   : (m == 3) ? s3 : (m == 4) ? s4 : s5;
    float4 v = *(const float4*)(s + e);
    int row = e >> 7, c = e & 127;
    int ct = row >> 4, li = row & 15;
    int ks = c >> 5, quad = (c >> 3) & 3, j = c & 7;   // j in {0,4}
    ushort4 u;
    u.x = f2bf(v.x); u.y = f2bf(v.y); u.z = f2bf(v.z); u.w = f2bf(v.w);
    *(ushort4*)(dst + m * 16384 + ((size_t)((ct * 4 + ks) * 64 + quad * 16 + li)) * 8 + j) = u;
}

// ---------- Barrier-free MFMA projection, split 4 ways ----------
// grid = (ceil(N/64), path, ct-half).  path 0: input t, matrices {Qa,Ka,Wt};
// path 1: input x, matrices {Qb,Kb,Wx}.  Each wave: 16 rows, 3 phases,
// 64 output channels per phase (its ct-half), acc[4], 16 prefetched frags.
// Output layouts (concatenated halves):
//   qa, qb : [N][128]
//   kab    : [N][256] = [ ka(128) | kb(128) ]
//   twxw   : [N][256] = [ tw(128) | xw(128) ]
#define TLROW 72   // LDS row stride in ushorts (144 B: 16B-aligned rows)
__global__ __launch_bounds__(256, 4) void proj_mfma(
    const float* __restrict__ in_t, const float* __restrict__ in_x, int N,
    const unsigned short* __restrict__ Wbf,
    const float* __restrict__ Qa_b, const float* __restrict__ Ka_b,
    const float* __restrict__ Qb_b, const float* __restrict__ Kb_b,
    unsigned short* __restrict__ qa, unsigned short* __restrict__ qb,
    unsigned short* __restrict__ kab, unsigned short* __restrict__ twxw)
{
    __shared__ __align__(16) unsigned short tile[4][2][16 * TLROW];  // 18432 B

    const int wave = threadIdx.x >> 6;
    const int lane = threadIdx.x & 63;
    const int li = lane & 15, quad = lane >> 4;
    const int p = blockIdx.y;        // 0 = t-path, 1 = x-path
    const int cth = blockIdx.z;      // ct-half: channels [cth*64, cth*64+64)
    const int r0 = (blockIdx.x * 4 + wave) * 16;
    if (r0 >= N) return;
    const int r = r0 + li;
    const bool rv = r < N;

    // ---- load this path's input row fragments (fp32 -> bf16 in regs) ----
    frag8 bt[4];
    {
        const float* inp = p ? in_x : in_t;
        const float* st = inp + (size_t)r * 128 + quad * 8;
#pragma unroll
        for (int ks = 0; ks < 4; ks++) {
            float4 lo = make_float4(0.f, 0.f, 0.f, 0.f), hi = lo;
            if (rv) {
                lo = *(const float4*)(st + ks * 32);
                hi = *(const float4*)(st + ks * 32 + 4);
            }
            frag8 f;
            f[0] = (short)f2bf(lo.x); f[1] = (short)f2bf(lo.y);
            f[2] = (short)f2bf(lo.z); f[3] = (short)f2bf(lo.w);
            f[4] = (short)f2bf(hi.x); f[5] = (short)f2bf(hi.y);
            f[6] = (short)f2bf(hi.z); f[7] = (short)f2bf(hi.w);
            bt[ks] = f;
        }
    }

    int buf = 0;
    auto phase = [&](int m, const float* bias,
                     unsigned short* dst, int rstride, int coff) {
        // base of this matrix's ct-half in permuted fragment layout
        const unsigned short* wb = Wbf + (size_t)m * 16384 + (size_t)cth * 8192
                                 + (size_t)lane * 8;
        // prefetch the entire phase's 16 A-fragments (coalesced 1 KB reads)
        frag8 af[16];
#pragma unroll
        for (int u = 0; u < 16; u++)
            af[u] = *(const frag8*)(wb + u * 512);

        fragf4 acc[4];
#pragma unroll
        for (int ct = 0; ct < 4; ct++) acc[ct] = (fragf4){0.f, 0.f, 0.f, 0.f};
#pragma unroll
        for (int ct = 0; ct < 4; ct++) {
#pragma unroll
            for (int ks = 0; ks < 4; ks++)
                acc[ct] = __builtin_amdgcn_mfma_f32_16x16x32_bf16(
                    af[ct * 4 + ks], bt[ks], acc[ct], 0, 0, 0);
        }

        // D-layout: lane(li,quad) holds node row li, tile cols ct*16+quad*4..+3
        unsigned short* lt = &tile[wave][buf][0];
#pragma unroll
        for (int ct = 0; ct < 4; ct++) {
            const int c = ct * 16 + quad * 4;          // col within 64-wide tile
            float4 bv = make_float4(0.f, 0.f, 0.f, 0.f);
            if (bias) bv = *(const float4*)(bias + cth * 64 + c);
            ushort4 u;
            u.x = f2bf(acc[ct][0] + bv.x);
            u.y = f2bf(acc[ct][1] + bv.y);
            u.z = f2bf(acc[ct][2] + bv.z);
            u.w = f2bf(acc[ct][3] + bv.w);
            *(ushort4*)&lt[li * TLROW + c] = u;
        }
        // wave-internal readback (in-order DS pipe; no barrier needed)
#pragma unroll
        for (int it = 0; it < 2; it++) {
            const int rr = it * 8 + (lane >> 3);
            const int cg = lane & 7;
            if (r0 + rr < N) {
                uint4 v = *(const uint4*)&lt[rr * TLROW + cg * 8];
                *(uint4*)(dst + (size_t)(r0 + rr) * rstride + coff + cg * 8) = v;
            }
        }
        buf ^= 1;
    };

    const int ch = cth * 64;
    if (p == 0) {
        phase(0, Qa_b, qa,   128, ch);
        phase(1, Ka_b, kab,  256, ch);
        phase(2, nullptr, twxw, 256, ch);
    } else {
        phase(3, Qb_b, qb,   128, ch);
        phase(4, Kb_b, kab,  256, 128 + ch);
        phase(5, nullptr, twxw, 256, 128 + ch);
    }
}

// ---------- CSR build ----------
__global__ __launch_bounds__(256) void hist_k(const int* __restrict__ row, int* __restrict__ deg, int E) {
    int e = blockIdx.x * 256 + threadIdx.x;
    if (e < E) atomicAdd(&deg[row[e]], 1);
}

#define SCAN_CHUNK 2048

__device__ __forceinline__ int wave_incl_scan(int v, int lane) {
#pragma unroll
    for (int d = 1; d < 64; d <<= 1) {
        int u = __shfl_up(v, d, 64);
        if (lane >= d) v += u;
    }
    return v;
}

__global__ __launch_bounds__(256) void scan_partial(const int* __restrict__ deg,
                                                    int* __restrict__ partial, int N) {
    const int tid = threadIdx.x;
    const int base = blockIdx.x * SCAN_CHUNK + tid * 8;
    int s = 0;
#pragma unroll
    for (int j = 0; j < 8; j++) {
        int i = base + j;
        s += (i < N) ? deg[i] : 0;
    }
    const int lane = tid & 63;
    s = wave_incl_scan(s, lane);
    __shared__ int wsum[4];
    if (lane == 63) wsum[tid >> 6] = s;
    __syncthreads();
    if (tid == 0) partial[blockIdx.x] = wsum[0] + wsum[1] + wsum[2] + wsum[3];
}

__global__ __launch_bounds__(64) void scan_base(int* __restrict__ partial, int nb,
                                                int* __restrict__ offs, int N) {
    const int lane = threadIdx.x;
    int v = (lane < nb) ? partial[lane] : 0;
    int inc = wave_incl_scan(v, lane);
    if (lane < nb) partial[lane] = inc - v;
    if (lane == 63) offs[N] = inc;
}

__global__ __launch_bounds__(256) void scan_final(const int* __restrict__ deg,
                                                  const int* __restrict__ partial,
                                                  int* __restrict__ offs,
                                                  int* __restrict__ cursor, int N) {
    const int tid = threadIdx.x;
    const int lane = tid & 63;
    const int wv = tid >> 6;
    const int base = blockIdx.x * SCAN_CHUNK + tid * 8;
    int v[8];
    int s = 0;
#pragma unroll
    for (int j = 0; j < 8; j++) {
        int i = base + j;
        v[j] = (i < N) ? deg[i] : 0;
        s += v[j];
    }
    int incl = wave_incl_scan(s, lane);
    __shared__ int wsum[4];
    if (lane == 63) wsum[wv] = incl;
    __syncthreads();
    int wbase = 0;
#pragma unroll
    for (int w = 0; w < 4; w++) wbase += (w < wv) ? wsum[w] : 0;
    int run = partial[blockIdx.x] + wbase + incl - s;
#pragma unroll
    for (int j = 0; j < 8; j++) {
        int i = base + j;
        if (i < N) { offs[i] = run; cursor[i] = run; }
        run += v[j];
    }
}

__global__ __launch_bounds__(256) void scatter_k(const int* __restrict__ row,
                                                 const int* __restrict__ col,
                                                 int* __restrict__ cursor,
                                                 int* __restrict__ csr_col, int E) {
    int e = blockIdx.x * 256 + threadIdx.x;
    if (e < E) {
        int p = atomicAdd(&cursor[row[e]], 1);
        csr_col[p] = col[e];
    }
}

// ---------- Fused edge scores + online softmax + V-aggregation ----------
__global__ __launch_bounds__(256) void edge_fused(
    const unsigned short* __restrict__ qa, const unsigned short* __restrict__ qb,
    const unsigned short* __restrict__ kab, const unsigned short* __restrict__ twxw,
    const int* __restrict__ csr_col, const int* __restrict__ offs,
    float* __restrict__ out_x, float* __restrict__ out_t, int N)
{
    const int n = blockIdx.x * 4 + (threadIdx.x >> 6);
    if (n >= N) return;
    const int lane = threadIdx.x & 63;
    const int g = lane >> 4, sub = lane & 15;
    const int s = offs[n], end = offs[n + 1];

    float qaf[8], qbf[8];
    {
        uint4 a = *(const uint4*)(qa + (size_t)n * 128 + sub * 8);
        uint4 b = *(const uint4*)(qb + (size_t)n * 128 + sub * 8);
        float2 f;
        f = bf2x(a.x); qaf[0] = f.x; qaf[1] = f.y;
        f = bf2x(a.y); qaf[2] = f.x; qaf[3] = f.y;
        f = bf2x(a.z); qaf[4] = f.x; qaf[5] = f.y;
        f = bf2x(a.w); qaf[6] = f.x; qaf[7] = f.y;
        f = bf2x(b.x); qbf[0] = f.x; qbf[1] = f.y;
        f = bf2x(b.y); qbf[2] = f.x; qbf[3] = f.y;
        f = bf2x(b.z); qbf[4] = f.x; qbf[5] = f.y;
        f = bf2x(b.w); qbf[6] = f.x; qbf[7] = f.y;
    }

    const float scale = 0.08838834764831845f;  // 1/sqrt(128)
    float m_a = -1e30f, d_a = 0.f, m_b = -1e30f, d_b = 0.f;
    float at0 = 0.f, at1 = 0.f, ax0 = 0.f, ax1 = 0.f;

    for (int i0 = s; i0 < end; i0 += 4) {
        const int i = i0 + g;
        const int c = csr_col[(i < end) ? i : (end - 1)];

        int cj[4];
#pragma unroll
        for (int j = 0; j < 4; j++) cj[j] = __shfl(c, j * 16, 64);
        unsigned int gvt[4], gvx[4];
#pragma unroll
        for (int j = 0; j < 4; j++) {
            const unsigned short* vp = twxw + (size_t)cj[j] * 256 + lane * 2;
            gvt[j] = *(const unsigned int*)vp;
            gvx[j] = *(const unsigned int*)(vp + 128);
        }

        const unsigned short* kp = kab + (size_t)c * 256 + sub * 8;
        uint4 ka4 = *(const uint4*)kp;
        uint4 kb4 = *(const uint4*)(kp + 128);
        float pa = 0.f, pb = 0.f;
        {
            float2 f;
            f = bf2x(ka4.x); pa = fmaf(qaf[0], f.x, fmaf(qaf[1], f.y, pa));
            f = bf2x(ka4.y); pa = fmaf(qaf[2], f.x, fmaf(qaf[3], f.y, pa));
            f = bf2x(ka4.z); pa = fmaf(qaf[4], f.x, fmaf(qaf[5], f.y, pa));
            f = bf2x(ka4.w); pa = fmaf(qaf[6], f.x, fmaf(qaf[7], f.y, pa));
            f = bf2x(kb4.x); pb = fmaf(qbf[0], f.x, fmaf(qbf[1], f.y, pb));
            f = bf2x(kb4.y); pb = fmaf(qbf[2], f.x, fmaf(qbf[3], f.y, pb));
            f = bf2x(kb4.z); pb = fmaf(qbf[4], f.x, fmaf(qbf[5], f.y, pb));
            f = bf2x(kb4.w); pb = fmaf(qbf[6], f.x, fmaf(qbf[7], f.y, pb));
        }
#pragma unroll
        for (int off = 1; off <= 8; off <<= 1) {
            pa += __shfl_xor(pa, off, 64);
            pb += __shfl_xor(pb, off, 64);
        }
        pa *= scale; pb *= scale;

        const int nv = min(4, end - i0);   // wave-uniform
#pragma unroll
        for (int j = 0; j < 4; j++) {
            if (j < nv) {
                float pja = __shfl(pa, j * 16, 64);
                float pjb = __shfl(pb, j * 16, 64);
                float2 tf = bf2x(gvt[j]);
                float2 xf = bf2x(gvx[j]);
                float mna = fmaxf(m_a, pja);
                float al = __expf(m_a - mna), wa = __expf(pja - mna);
                d_a = d_a * al + wa; m_a = mna;
                at0 = at0 * al + wa * tf.x;
                at1 = at1 * al + wa * tf.y;
                float mnb = fmaxf(m_b, pjb);
                float bl = __expf(m_b - mnb), wb = __expf(pjb - mnb);
                d_b = d_b * bl + wb; m_b = mnb;
                ax0 = ax0 * bl + wb * xf.x;
                ax1 = ax1 * bl + wb * xf.y;
            }
        }
    }
    const float ra = (d_a > 0.f) ? 1.f / d_a : 0.f;
    const float rb = (d_b > 0.f) ? 1.f / d_b : 0.f;
    *(float2*)(out_t + (size_t)n * 128 + lane * 2) = make_float2(at0 * ra, at1 * ra);
    *(float2*)(out_x + (size_t)n * 128 + lane * 2) = make_float2(ax0 * rb, ax1 * rb);
}

extern "C" void kernel_launch(void* const* d_in, const int* in_sizes, int n_in,
                              void* d_out, int out_size, void* d_ws, size_t ws_size,
                              hipStream_t stream) {
    const float* x    = (const float*)d_in[0];
    const float* t    = (const float*)d_in[1];
    const int*   ei   = (const int*)d_in[2];
    const float* W_x  = (const float*)d_in[3];
    const float* W_t  = (const float*)d_in[4];
    const float* Qa_w = (const float*)d_in[5];
    const float* Qa_b = (const float*)d_in[6];
    const float* Ka_w = (const float*)d_in[7];
    const float* Ka_b = (const float*)d_in[8];
    const float* Qb_w = (const float*)d_in[9];
    const float* Qb_b = (const float*)d_in[10];
    const float* Kb_w = (const float*)d_in[11];
    const float* Kb_b = (const float*)d_in[12];

    const int N = in_sizes[0] / 128;
    const int E = in_sizes[2] / 2;
    const int* row = ei;
    const int* col = ei + E;

    char* ws = (char*)d_ws;
    size_t off = 0;
    auto carve = [&](size_t bytes) -> void* {
        void* p = ws + off;
        off += (bytes + 255) & ~(size_t)255;
        return p;
    };
    unsigned short* qa   = (unsigned short*)carve((size_t)N * 128 * 2);
    unsigned short* qb   = (unsigned short*)carve((size_t)N * 128 * 2);
    unsigned short* kab  = (unsigned short*)carve((size_t)N * 256 * 2);
    unsigned short* twxw = (unsigned short*)carve((size_t)N * 256 * 2);
    int* deg      = (int*)carve((size_t)N * 4);
    int* cursor   = (int*)carve((size_t)N * 4);
    int* offs     = (int*)carve((size_t)(N + 1) * 4);
    int* csr_col  = (int*)carve((size_t)E * 4);
    const int nscan = (N + SCAN_CHUNK - 1) / SCAN_CHUNK;
    int* partial  = (int*)carve((size_t)nscan * 4);
    unsigned short* Wbf = (unsigned short*)carve((size_t)6 * 16384 * 2);

    hipMemsetAsync(deg, 0, (size_t)N * 4, stream);

    dim3 b256(256);
    // weight order: [Qa, Ka, Wt, Qb, Kb, Wx], permuted fragment layout
    convert_w<<<dim3(96), b256, 0, stream>>>(Qa_w, Ka_w, W_t, Qb_w, Kb_w, W_x, Wbf);

    proj_mfma<<<dim3((N + 63) / 64, 2, 2), b256, 0, stream>>>(
        t, x, N, Wbf, Qa_b, Ka_b, Qb_b, Kb_b, qa, qb, kab, twxw);

    hist_k<<<dim3((E + 255) / 256), b256, 0, stream>>>(row, deg, E);
    scan_partial<<<dim3(nscan), b256, 0, stream>>>(deg, partial, N);
    scan_base<<<dim3(1), dim3(64), 0, stream>>>(partial, nscan, offs, N);
    scan_final<<<dim3(nscan), b256, 0, stream>>>(deg, partial, offs, cursor, N);
    scatter_k<<<dim3((E + 255) / 256), b256, 0, stream>>>(row, col, cursor, csr_col, E);

    float* out_x = (float*)d_out;
    float* out_t = out_x + (size_t)N * 128;
    edge_fused<<<dim3((N + 3) / 4), b256, 0, stream>>>(
        qa, qb, kab, twxw, csr_col, offs, out_x, out_t, N);
}

// Round 3
// 262.687 us; speedup vs baseline: 1.2810x; 1.0181x over previous
//
#include <hip/hip_runtime.h>

// ---------- bf16 helpers ----------
__device__ __forceinline__ unsigned short f2bf(float f) {
    unsigned int x = __float_as_uint(f);
    x += 0x7fffu + ((x >> 16) & 1u);
    return (unsigned short)(x >> 16);
}
__device__ __forceinline__ float2 bf2x(unsigned int u) {
    float2 r;
    r.x = __uint_as_float(u << 16);
    r.y = __uint_as_float(u & 0xffff0000u);
    return r;
}
__device__ __forceinline__ float bcastf(float v, int l) {
    return __uint_as_float(__builtin_amdgcn_readlane(__float_as_uint(v), l));
}
template <int PAT>
__device__ __forceinline__ float swzadd(float v) {
    return v + __uint_as_float(__builtin_amdgcn_ds_swizzle(__float_as_uint(v), PAT));
}

typedef __attribute__((ext_vector_type(8))) short frag8;   // 8 bf16
typedef __attribute__((ext_vector_type(4))) float fragf4;  // 4 fp32 acc

// ---------- fused: convert 6 weight matrices (96 blocks) + degree histogram ----------
// weight order: [Qa, Ka, Wt, Qb, Kb, Wx]
// Permuted fragment layout: element (row, col) of matrix m at
//   m*16384 + ((ct*4 + ks)*64 + quad*16 + li)*8 + j
// (ct=row>>4, li=row&15, ks=col>>5, quad=(col>>3)&3, j=col&7) so a wave's
// MFMA A-fragment load is base + lane*16 bytes: one coalesced 1 KB read.
__global__ __launch_bounds__(256) void convert_hist(
    const float* __restrict__ s0, const float* __restrict__ s1,
    const float* __restrict__ s2, const float* __restrict__ s3,
    const float* __restrict__ s4, const float* __restrict__ s5,
    unsigned short* __restrict__ dst,
    const int* __restrict__ row, int* __restrict__ deg, int E)
{
    const int b = blockIdx.x;
    if (b < 96) {
        int id = b * 256 + threadIdx.x;
        int m = id >> 12;
        int e = (id & 4095) * 4;
        const float* s = (m == 0) ? s0 : (m == 1) ? s1 : (m == 2) ? s2
                       : (m == 3) ? s3 : (m == 4) ? s4 : s5;
        float4 v = *(const float4*)(s + e);
        int r = e >> 7, c = e & 127;
        int ct = r >> 4, li = r & 15;
        int ks = c >> 5, quad = (c >> 3) & 3, j = c & 7;
        ushort4 u;
        u.x = f2bf(v.x); u.y = f2bf(v.y); u.z = f2bf(v.z); u.w = f2bf(v.w);
        *(ushort4*)(dst + m * 16384 +
                    ((size_t)((ct * 4 + ks) * 64 + quad * 16 + li)) * 8 + j) = u;
    } else {
        int e = (b - 96) * 256 + threadIdx.x;
        if (e < E) atomicAdd(&deg[row[e]], 1);
    }
}

// ---------- fused: CSR scatter (nScat blocks) + MFMA projection ----------
// scatter first so its atomics overlap proj's latency-bound phases.
// proj: flattened grid; pb = bx + nbx*(p + 2*cth).
//   path 0: input t, matrices {Qa,Ka,Wt}; path 1: input x, {Qb,Kb,Wx}.
// Output layouts: qa,qb:[N][128]; kab:[N][256]=[ka|kb]; twxw:[N][256]=[tw|xw]
#define TLROW 72   // LDS row stride in ushorts (144 B: 16B-aligned rows)
__global__ __launch_bounds__(256, 4) void proj_scatter(
    const float* __restrict__ in_t, const float* __restrict__ in_x, int N,
    const unsigned short* __restrict__ Wbf,
    const float* __restrict__ Qa_b, const float* __restrict__ Ka_b,
    const float* __restrict__ Qb_b, const float* __restrict__ Kb_b,
    unsigned short* __restrict__ qa, unsigned short* __restrict__ qb,
    unsigned short* __restrict__ kab, unsigned short* __restrict__ twxw,
    const int* __restrict__ erow, const int* __restrict__ ecol,
    int* __restrict__ cursor, int* __restrict__ csr_col, int E,
    int nScat, int nbx)
{
    __shared__ __align__(16) unsigned short tile[4][2][16 * TLROW];  // 18432 B

    if ((int)blockIdx.x < nScat) {
        int e = blockIdx.x * 256 + threadIdx.x;
        if (e < E) {
            int p = atomicAdd(&cursor[erow[e]], 1);
            csr_col[p] = ecol[e];
        }
        return;
    }
    const int pb = blockIdx.x - nScat;
    const int bx = pb % nbx;
    const int rest = pb / nbx;
    const int p = rest & 1;          // 0 = t-path, 1 = x-path
    const int cth = rest >> 1;       // channel half

    const int wave = threadIdx.x >> 6;
    const int lane = threadIdx.x & 63;
    const int li = lane & 15, quad = lane >> 4;
    const int r0 = (bx * 4 + wave) * 16;
    if (r0 >= N) return;
    const int r = r0 + li;
    const bool rv = r < N;

    // ---- load this path's input row fragments (fp32 -> bf16 in regs) ----
    frag8 bt[4];
    {
        const float* inp = p ? in_x : in_t;
        const float* st = inp + (size_t)r * 128 + quad * 8;
#pragma unroll
        for (int ks = 0; ks < 4; ks++) {
            float4 lo = make_float4(0.f, 0.f, 0.f, 0.f), hi = lo;
            if (rv) {
                lo = *(const float4*)(st + ks * 32);
                hi = *(const float4*)(st + ks * 32 + 4);
            }
            frag8 f;
            f[0] = (short)f2bf(lo.x); f[1] = (short)f2bf(lo.y);
            f[2] = (short)f2bf(lo.z); f[3] = (short)f2bf(lo.w);
            f[4] = (short)f2bf(hi.x); f[5] = (short)f2bf(hi.y);
            f[6] = (short)f2bf(hi.z); f[7] = (short)f2bf(hi.w);
            bt[ks] = f;
        }
    }

    int buf = 0;
    auto phase = [&](int m, const float* bias,
                     unsigned short* dst, int rstride, int coff) {
        const unsigned short* wb = Wbf + (size_t)m * 16384 + (size_t)cth * 8192
                                 + (size_t)lane * 8;
        frag8 af[16];
#pragma unroll
        for (int u = 0; u < 16; u++)
            af[u] = *(const frag8*)(wb + u * 512);

        fragf4 acc[4];
#pragma unroll
        for (int ct = 0; ct < 4; ct++) acc[ct] = (fragf4){0.f, 0.f, 0.f, 0.f};
#pragma unroll
        for (int ct = 0; ct < 4; ct++) {
#pragma unroll
            for (int ks = 0; ks < 4; ks++)
                acc[ct] = __builtin_amdgcn_mfma_f32_16x16x32_bf16(
                    af[ct * 4 + ks], bt[ks], acc[ct], 0, 0, 0);
        }

        unsigned short* lt = &tile[wave][buf][0];
#pragma unroll
        for (int ct = 0; ct < 4; ct++) {
            const int c = ct * 16 + quad * 4;
            float4 bv = make_float4(0.f, 0.f, 0.f, 0.f);
            if (bias) bv = *(const float4*)(bias + cth * 64 + c);
            ushort4 u;
            u.x = f2bf(acc[ct][0] + bv.x);
            u.y = f2bf(acc[ct][1] + bv.y);
            u.z = f2bf(acc[ct][2] + bv.z);
            u.w = f2bf(acc[ct][3] + bv.w);
            *(ushort4*)&lt[li * TLROW + c] = u;
        }
        // wave-internal readback (in-order DS pipe; no barrier needed)
#pragma unroll
        for (int it = 0; it < 2; it++) {
            const int rr = it * 8 + (lane >> 3);
            const int cg = lane & 7;
            if (r0 + rr < N) {
                uint4 v = *(const uint4*)&lt[rr * TLROW + cg * 8];
                *(uint4*)(dst + (size_t)(r0 + rr) * rstride + coff + cg * 8) = v;
            }
        }
        buf ^= 1;
    };

    const int ch = cth * 64;
    if (p == 0) {
        phase(0, Qa_b, qa,   128, ch);
        phase(1, Ka_b, kab,  256, ch);
        phase(2, nullptr, twxw, 256, ch);
    } else {
        phase(3, Qb_b, qb,   128, ch);
        phase(4, Kb_b, kab,  256, 128 + ch);
        phase(5, nullptr, twxw, 256, 128 + ch);
    }
}

// ---------- CSR scan ----------
#define SCAN_CHUNK 2048

__device__ __forceinline__ int wave_incl_scan(int v, int lane) {
#pragma unroll
    for (int d = 1; d < 64; d <<= 1) {
        int u = __shfl_up(v, d, 64);
        if (lane >= d) v += u;
    }
    return v;
}

__global__ __launch_bounds__(256) void scan_partial(const int* __restrict__ deg,
                                                    int* __restrict__ partial, int N) {
    const int tid = threadIdx.x;
    const int base = blockIdx.x * SCAN_CHUNK + tid * 8;
    int s = 0;
#pragma unroll
    for (int j = 0; j < 8; j++) {
        int i = base + j;
        s += (i < N) ? deg[i] : 0;
    }
    const int lane = tid & 63;
    s = wave_incl_scan(s, lane);
    __shared__ int wsum[4];
    if (lane == 63) wsum[tid >> 6] = s;
    __syncthreads();
    if (tid == 0) partial[blockIdx.x] = wsum[0] + wsum[1] + wsum[2] + wsum[3];
}

__global__ __launch_bounds__(64) void scan_base(int* __restrict__ partial, int nb,
                                                int* __restrict__ offs, int N) {
    const int lane = threadIdx.x;
    int v = (lane < nb) ? partial[lane] : 0;
    int inc = wave_incl_scan(v, lane);
    if (lane < nb) partial[lane] = inc - v;
    if (lane == 63) offs[N] = inc;
}

__global__ __launch_bounds__(256) void scan_final(const int* __restrict__ deg,
                                                  const int* __restrict__ partial,
                                                  int* __restrict__ offs,
                                                  int* __restrict__ cursor, int N) {
    const int tid = threadIdx.x;
    const int lane = tid & 63;
    const int wv = tid >> 6;
    const int base = blockIdx.x * SCAN_CHUNK + tid * 8;
    int v[8];
    int s = 0;
#pragma unroll
    for (int j = 0; j < 8; j++) {
        int i = base + j;
        v[j] = (i < N) ? deg[i] : 0;
        s += v[j];
    }
    int incl = wave_incl_scan(s, lane);
    __shared__ int wsum[4];
    if (lane == 63) wsum[wv] = incl;
    __syncthreads();
    int wbase = 0;
#pragma unroll
    for (int w = 0; w < 4; w++) wbase += (w < wv) ? wsum[w] : 0;
    int run = partial[blockIdx.x] + wbase + incl - s;
#pragma unroll
    for (int j = 0; j < 8; j++) {
        int i = base + j;
        if (i < N) { offs[i] = run; cursor[i] = run; }
        run += v[j];
    }
}

// ---------- Fused edge scores + softmax + V-aggregation ----------
// Softmax is shift-invariant; scores here are tiny (|s| << 1), so we use
// exp(min(s, 60)) directly (clamp never triggers on valid data, keeps any
// input finite) and skip the online-max rescaling entirely.
// Lane layout: 16-lane group g handles edge i0+g's K-dot; for V-accumulation
// lanes 0..31 own tw (alpha side, 4 channels each), lanes 32..63 own xw.
__global__ __launch_bounds__(256) void edge_fused(
    const unsigned short* __restrict__ qa, const unsigned short* __restrict__ qb,
    const unsigned short* __restrict__ kab, const unsigned short* __restrict__ twxw,
    const int* __restrict__ csr_col, const int* __restrict__ offs,
    float* __restrict__ out_x, float* __restrict__ out_t, int N)
{
    const int n = blockIdx.x * 4 + (threadIdx.x >> 6);
    if (n >= N) return;
    const int lane = threadIdx.x & 63;
    const int g = lane >> 4, sub = lane & 15;
    const int s = offs[n], end = offs[n + 1];

    float qaf[8], qbf[8];
    {
        uint4 a = *(const uint4*)(qa + (size_t)n * 128 + sub * 8);
        uint4 b = *(const uint4*)(qb + (size_t)n * 128 + sub * 8);
        float2 f;
        f = bf2x(a.x); qaf[0] = f.x; qaf[1] = f.y;
        f = bf2x(a.y); qaf[2] = f.x; qaf[3] = f.y;
        f = bf2x(a.z); qaf[4] = f.x; qaf[5] = f.y;
        f = bf2x(a.w); qaf[6] = f.x; qaf[7] = f.y;
        f = bf2x(b.x); qbf[0] = f.x; qbf[1] = f.y;
        f = bf2x(b.y); qbf[2] = f.x; qbf[3] = f.y;
        f = bf2x(b.z); qbf[4] = f.x; qbf[5] = f.y;
        f = bf2x(b.w); qbf[6] = f.x; qbf[7] = f.y;
    }

    const float scale = 0.08838834764831845f;  // 1/sqrt(128)
    const bool xside = lane >= 32;
    const unsigned short* vbase = twxw + lane * 4;  // this lane's 4-channel slot
    float acc0 = 0.f, acc1 = 0.f, acc2 = 0.f, acc3 = 0.f, dd = 0.f;

    if (end > s) {
        int c = csr_col[min(s + g, end - 1)];
        for (int i0 = s; i0 < end; i0 += 4) {
            const bool val = (i0 + g) < end;
            // software-pipeline next iteration's column index
            const int idx = i0 + 4 + g;
            const int cn = csr_col[(idx < end) ? idx : (end - 1)];

            // V gather: scalar row base (readlane) + per-lane channel offset
            const int c0 = __builtin_amdgcn_readlane(c, 0);
            const int c1 = __builtin_amdgcn_readlane(c, 16);
            const int c2 = __builtin_amdgcn_readlane(c, 32);
            const int c3 = __builtin_amdgcn_readlane(c, 48);
            const uint2 gv0 = *(const uint2*)(vbase + (size_t)c0 * 256);
            const uint2 gv1 = *(const uint2*)(vbase + (size_t)c1 * 256);
            const uint2 gv2 = *(const uint2*)(vbase + (size_t)c2 * 256);
            const uint2 gv3 = *(const uint2*)(vbase + (size_t)c3 * 256);

            // K gather + dual dot product
            const unsigned short* kp = kab + (size_t)c * 256 + sub * 8;
            const uint4 ka4 = *(const uint4*)kp;
            const uint4 kb4 = *(const uint4*)(kp + 128);
            float pa = 0.f, pb = 0.f;
            {
                float2 f;
                f = bf2x(ka4.x); pa = fmaf(qaf[0], f.x, fmaf(qaf[1], f.y, pa));
                f = bf2x(ka4.y); pa = fmaf(qaf[2], f.x, fmaf(qaf[3], f.y, pa));
                f = bf2x(ka4.z); pa = fmaf(qaf[4], f.x, fmaf(qaf[5], f.y, pa));
                f = bf2x(ka4.w); pa = fmaf(qaf[6], f.x, fmaf(qaf[7], f.y, pa));
                f = bf2x(kb4.x); pb = fmaf(qbf[0], f.x, fmaf(qbf[1], f.y, pb));
                f = bf2x(kb4.y); pb = fmaf(qbf[2], f.x, fmaf(qbf[3], f.y, pb));
                f = bf2x(kb4.z); pb = fmaf(qbf[4], f.x, fmaf(qbf[5], f.y, pb));
                f = bf2x(kb4.w); pb = fmaf(qbf[6], f.x, fmaf(qbf[7], f.y, pb));
            }
            // 16-lane xor reduction via single-inst ds_swizzle (literal patterns)
            pa = swzadd<0x041F>(pa); pb = swzadd<0x041F>(pb);
            pa = swzadd<0x081F>(pa); pb = swzadd<0x081F>(pb);
            pa = swzadd<0x101F>(pa); pb = swzadd<0x101F>(pb);
            pa = swzadd<0x201F>(pa); pb = swzadd<0x201F>(pb);

            const float ea = val ? __expf(fminf(pa * scale, 60.f)) : 0.f;
            const float eb = val ? __expf(fminf(pb * scale, 60.f)) : 0.f;

            // per-edge weight for this lane's side (broadcasts land in SGPRs)
            const float w0 = xside ? bcastf(eb, 0)  : bcastf(ea, 0);
            const float w1 = xside ? bcastf(eb, 16) : bcastf(ea, 16);
            const float w2 = xside ? bcastf(eb, 32) : bcastf(ea, 32);
            const float w3 = xside ? bcastf(eb, 48) : bcastf(ea, 48);

            float2 lo, hi;
            lo = bf2x(gv0.x); hi = bf2x(gv0.y);
            dd += w0;
            acc0 = fmaf(w0, lo.x, acc0); acc1 = fmaf(w0, lo.y, acc1);
            acc2 = fmaf(w0, hi.x, acc2); acc3 = fmaf(w0, hi.y, acc3);
            lo = bf2x(gv1.x); hi = bf2x(gv1.y);
            dd += w1;
            acc0 = fmaf(w1, lo.x, acc0); acc1 = fmaf(w1, lo.y, acc1);
            acc2 = fmaf(w1, hi.x, acc2); acc3 = fmaf(w1, hi.y, acc3);
            lo = bf2x(gv2.x); hi = bf2x(gv2.y);
            dd += w2;
            acc0 = fmaf(w2, lo.x, acc0); acc1 = fmaf(w2, lo.y, acc1);
            acc2 = fmaf(w2, hi.x, acc2); acc3 = fmaf(w2, hi.y, acc3);
            lo = bf2x(gv3.x); hi = bf2x(gv3.y);
            dd += w3;
            acc0 = fmaf(w3, lo.x, acc0); acc1 = fmaf(w3, lo.y, acc1);
            acc2 = fmaf(w3, hi.x, acc2); acc3 = fmaf(w3, hi.y, acc3);

            c = cn;
        }
    }

    const float r = (dd > 0.f) ? 1.f / dd : 0.f;
    float4 o = make_float4(acc0 * r, acc1 * r, acc2 * r, acc3 * r);
    float* op = xside ? (out_x + (size_t)n * 128 + (lane - 32) * 4)
                      : (out_t + (size_t)n * 128 + lane * 4);
    *(float4*)op = o;
}

extern "C" void kernel_launch(void* const* d_in, const int* in_sizes, int n_in,
                              void* d_out, int out_size, void* d_ws, size_t ws_size,
                              hipStream_t stream) {
    const float* x    = (const float*)d_in[0];
    const float* t    = (const float*)d_in[1];
    const int*   ei   = (const int*)d_in[2];
    const float* W_x  = (const float*)d_in[3];
    const float* W_t  = (const float*)d_in[4];
    const float* Qa_w = (const float*)d_in[5];
    const float* Qa_b = (const float*)d_in[6];
    const float* Ka_w = (const float*)d_in[7];
    const float* Ka_b = (const float*)d_in[8];
    const float* Qb_w = (const float*)d_in[9];
    const float* Qb_b = (const float*)d_in[10];
    const float* Kb_w = (const float*)d_in[11];
    const float* Kb_b = (const float*)d_in[12];

    const int N = in_sizes[0] / 128;
    const int E = in_sizes[2] / 2;
    const int* row = ei;
    const int* col = ei + E;

    char* ws = (char*)d_ws;
    size_t off = 0;
    auto carve = [&](size_t bytes) -> void* {
        void* p = ws + off;
        off += (bytes + 255) & ~(size_t)255;
        return p;
    };
    unsigned short* qa   = (unsigned short*)carve((size_t)N * 128 * 2);
    unsigned short* qb   = (unsigned short*)carve((size_t)N * 128 * 2);
    unsigned short* kab  = (unsigned short*)carve((size_t)N * 256 * 2);
    unsigned short* twxw = (unsigned short*)carve((size_t)N * 256 * 2);
    int* deg      = (int*)carve((size_t)N * 4);
    int* cursor   = (int*)carve((size_t)N * 4);
    int* offs     = (int*)carve((size_t)(N + 1) * 4);
    int* csr_col  = (int*)carve((size_t)E * 4);
    const int nscan = (N + SCAN_CHUNK - 1) / SCAN_CHUNK;
    int* partial  = (int*)carve((size_t)nscan * 4);
    unsigned short* Wbf = (unsigned short*)carve((size_t)6 * 16384 * 2);

    (void)hipMemsetAsync(deg, 0, (size_t)N * 4, stream);

    dim3 b256(256);
    const int nHist = (E + 255) / 256;
    convert_hist<<<dim3(96 + nHist), b256, 0, stream>>>(
        Qa_w, Ka_w, W_t, Qb_w, Kb_w, W_x, Wbf, row, deg, E);

    scan_partial<<<dim3(nscan), b256, 0, stream>>>(deg, partial, N);
    scan_base<<<dim3(1), dim3(64), 0, stream>>>(partial, nscan, offs, N);
    scan_final<<<dim3(nscan), b256, 0, stream>>>(deg, partial, offs, cursor, N);

    const int nbx = (N + 63) / 64;
    const int nScat = (E + 255) / 256;
    proj_scatter<<<dim3(nScat + nbx * 4), b256, 0, stream>>>(
        t, x, N, Wbf, Qa_b, Ka_b, Qb_b, Kb_b, qa, qb, kab, twxw,
        row, col, cursor, csr_col, E, nScat, nbx);

    float* out_x = (float*)d_out;
    float* out_t = out_x + (size_t)N * 128;
    edge_fused<<<dim3((N + 3) / 4), b256, 0, stream>>>(
        qa, qb, kab, twxw, csr_col, offs, out_x, out_t, N);
}